// Round 1
// baseline (1880.107 us; speedup 1.0000x reference)
//
#include <hip/hip_runtime.h>
#include <hip/hip_bf16.h>

// Problem constants (fixed by setup_inputs): B=2, Tq=1024, Tk=4096, DIM=1024,
// H=16, Hd=64, SCALE=0.125.
#define BATCH 2
#define TQ 1024
#define TK 4096
#define DIMSZ 1024
#define NH 16
#define HD 64
#define SCALE 0.125f

// ---------------------------------------------------------------------------
// Generic tiled fp32 GEMM-NT with bias: C[m,n] = sum_k A[m,k]*B[n,k] + bias[n]
// A: [M,K] row-major, B: [N,K] row-major. M,N multiples of 64, K mult of 16.
// 256 threads, 64x64 tile, 4x4 per-thread micro-tile.
// ---------------------------------------------------------------------------
__global__ __launch_bounds__(256) void gemm_nt_bias(
    const float* __restrict__ A, const float* __restrict__ B,
    const float* __restrict__ bias, float* __restrict__ C,
    int M, int N, int K) {
  __shared__ float As[64][17];
  __shared__ float Bs[64][17];
  const int t = threadIdx.x;
  const int tx = t & 15, ty = t >> 4;
  const int row0 = blockIdx.y * 64, col0 = blockIdx.x * 64;
  const int lcol = t & 15, lr = t >> 4;

  float acc[4][4] = {};
  for (int k0 = 0; k0 < K; k0 += 16) {
#pragma unroll
    for (int i = 0; i < 4; i++) {
      As[lr + 16 * i][lcol] = A[(long)(row0 + lr + 16 * i) * K + k0 + lcol];
      Bs[lr + 16 * i][lcol] = B[(long)(col0 + lr + 16 * i) * K + k0 + lcol];
    }
    __syncthreads();
#pragma unroll
    for (int kk = 0; kk < 16; kk++) {
      float a[4], b[4];
#pragma unroll
      for (int i = 0; i < 4; i++) a[i] = As[ty * 4 + i][kk];
#pragma unroll
      for (int j = 0; j < 4; j++) b[j] = Bs[tx * 4 + j][kk];
#pragma unroll
      for (int i = 0; i < 4; i++)
#pragma unroll
        for (int j = 0; j < 4; j++) acc[i][j] += a[i] * b[j];
    }
    __syncthreads();
  }
#pragma unroll
  for (int i = 0; i < 4; i++) {
    const int r = row0 + ty * 4 + i;
#pragma unroll
    for (int j = 0; j < 4; j++) {
      const int c = col0 + tx * 4 + j;
      C[(long)r * N + c] = acc[i][j] + bias[c];
    }
  }
}

// ---------------------------------------------------------------------------
// Batched scores: S[z, m, n] = SCALE * sum_d q[b,m,h*64+d] * k[b,n,h*64+d]
// z = b*16+h. Written to attn region [32, 1024, 4096].
// ---------------------------------------------------------------------------
__global__ __launch_bounds__(256) void scores_gemm(
    const float* __restrict__ qb, const float* __restrict__ kb,
    float* __restrict__ attn) {
  const int z = blockIdx.z;
  const int b = z >> 4, h = z & 15;
  const float* A = qb + (long)b * TQ * DIMSZ + h * HD;   // lda = DIMSZ
  const float* B = kb + (long)b * TK * DIMSZ + h * HD;   // ldb = DIMSZ
  float* C = attn + (long)z * TQ * TK;                    // ldc = TK

  __shared__ float As[64][17];
  __shared__ float Bs[64][17];
  const int t = threadIdx.x;
  const int tx = t & 15, ty = t >> 4;
  const int row0 = blockIdx.y * 64, col0 = blockIdx.x * 64;
  const int lcol = t & 15, lr = t >> 4;

  float acc[4][4] = {};
  for (int k0 = 0; k0 < HD; k0 += 16) {
#pragma unroll
    for (int i = 0; i < 4; i++) {
      As[lr + 16 * i][lcol] = A[(long)(row0 + lr + 16 * i) * DIMSZ + k0 + lcol];
      Bs[lr + 16 * i][lcol] = B[(long)(col0 + lr + 16 * i) * DIMSZ + k0 + lcol];
    }
    __syncthreads();
#pragma unroll
    for (int kk = 0; kk < 16; kk++) {
      float a[4], b2[4];
#pragma unroll
      for (int i = 0; i < 4; i++) a[i] = As[ty * 4 + i][kk];
#pragma unroll
      for (int j = 0; j < 4; j++) b2[j] = Bs[tx * 4 + j][kk];
#pragma unroll
      for (int i = 0; i < 4; i++)
#pragma unroll
        for (int j = 0; j < 4; j++) acc[i][j] += a[i] * b2[j];
    }
    __syncthreads();
  }
#pragma unroll
  for (int i = 0; i < 4; i++) {
    const int r = row0 + ty * 4 + i;
#pragma unroll
    for (int j = 0; j < 4; j++) {
      const int c = col0 + tx * 4 + j;
      C[(long)r * TK + c] = SCALE * acc[i][j];
    }
  }
}

// ---------------------------------------------------------------------------
// In-place row softmax over Tk=4096. One block (256 thr) per row; row staged
// in LDS (16 KB).
// ---------------------------------------------------------------------------
__global__ __launch_bounds__(256) void softmax_rows(float* __restrict__ attn) {
  __shared__ float srow[TK];
  __shared__ float wmax[4];
  __shared__ float wsum[4];
  const long base = (long)blockIdx.x * TK;
  const int t = threadIdx.x;

  float lmax = -1e30f;
  for (int i = t; i < TK; i += 256) {
    float x = attn[base + i];
    srow[i] = x;
    lmax = fmaxf(lmax, x);
  }
#pragma unroll
  for (int off = 32; off; off >>= 1) lmax = fmaxf(lmax, __shfl_xor(lmax, off));
  if ((t & 63) == 0) wmax[t >> 6] = lmax;
  __syncthreads();
  const float rmax = fmaxf(fmaxf(wmax[0], wmax[1]), fmaxf(wmax[2], wmax[3]));

  float lsum = 0.f;
  for (int i = t; i < TK; i += 256) {
    float e = __expf(srow[i] - rmax);
    srow[i] = e;
    lsum += e;
  }
#pragma unroll
  for (int off = 32; off; off >>= 1) lsum += __shfl_xor(lsum, off);
  if ((t & 63) == 0) wsum[t >> 6] = lsum;
  __syncthreads();
  const float inv = 1.f / (wsum[0] + wsum[1] + wsum[2] + wsum[3]);

  for (int i = t; i < TK; i += 256) attn[base + i] = srow[i] * inv;
}

// ---------------------------------------------------------------------------
// Batched PV: out[b, m, h*64+d] = sum_k attn[z, m, k] * v[b, k, h*64+d]
// GEMM-NN, K=4096, N=64 (one tile wide). 64x64 tile, 4x4 per thread.
// ---------------------------------------------------------------------------
__global__ __launch_bounds__(256) void pv_gemm(
    const float* __restrict__ attn, const float* __restrict__ vb,
    float* __restrict__ out) {
  const int z = blockIdx.z;
  const int b = z >> 4, h = z & 15;
  const float* A = attn + (long)z * TQ * TK;              // lda = TK
  const float* B = vb + (long)b * TK * DIMSZ + h * HD;    // ldb = DIMSZ
  float* C = out + (long)b * TQ * DIMSZ + h * HD;         // ldc = DIMSZ

  __shared__ float As[64][17];
  __shared__ float Bs[16][65];
  const int t = threadIdx.x;
  const int tx = t & 15, ty = t >> 4;
  const int row0 = blockIdx.y * 64;
  const int lcol = t & 15, lr = t >> 4;
  const int ld = t & 63, lk = t >> 6;

  float acc[4][4] = {};
  for (int k0 = 0; k0 < TK; k0 += 16) {
#pragma unroll
    for (int i = 0; i < 4; i++)
      As[lr + 16 * i][lcol] = A[(long)(row0 + lr + 16 * i) * TK + k0 + lcol];
#pragma unroll
    for (int i = 0; i < 4; i++)
      Bs[lk + 4 * i][ld] = B[(long)(k0 + lk + 4 * i) * DIMSZ + ld];
    __syncthreads();
#pragma unroll
    for (int kk = 0; kk < 16; kk++) {
      float a[4], b2[4];
#pragma unroll
      for (int i = 0; i < 4; i++) a[i] = As[ty * 4 + i][kk];
#pragma unroll
      for (int j = 0; j < 4; j++) b2[j] = Bs[kk][tx * 4 + j];
#pragma unroll
      for (int i = 0; i < 4; i++)
#pragma unroll
        for (int j = 0; j < 4; j++) acc[i][j] += a[i] * b2[j];
    }
    __syncthreads();
  }
#pragma unroll
  for (int i = 0; i < 4; i++)
#pragma unroll
    for (int j = 0; j < 4; j++)
      C[(long)(row0 + ty * 4 + i) * DIMSZ + tx * 4 + j] = acc[i][j];
}

// ---------------------------------------------------------------------------
// Residual + LayerNorm: out[r,:] = LN(query[r,:] + y[r,:]) * gamma + beta
// One block per row (1024 cols, 256 threads, 4 cols/thread).
// ---------------------------------------------------------------------------
__global__ __launch_bounds__(256) void residual_ln(
    const float* __restrict__ q, const float* __restrict__ y,
    const float* __restrict__ gamma, const float* __restrict__ beta,
    float* __restrict__ out) {
  __shared__ float w1[4];
  __shared__ float w2[4];
  const long base = (long)blockIdx.x * DIMSZ;
  const int t = threadIdx.x;

  float x[4];
  float s = 0.f;
#pragma unroll
  for (int i = 0; i < 4; i++) {
    const int c = t + i * 256;
    x[i] = q[base + c] + y[base + c];
    s += x[i];
  }
#pragma unroll
  for (int off = 32; off; off >>= 1) s += __shfl_xor(s, off);
  if ((t & 63) == 0) w1[t >> 6] = s;
  __syncthreads();
  const float mean = (w1[0] + w1[1] + w1[2] + w1[3]) * (1.f / DIMSZ);

  float vs = 0.f;
#pragma unroll
  for (int i = 0; i < 4; i++) {
    const float d = x[i] - mean;
    vs += d * d;
  }
#pragma unroll
  for (int off = 32; off; off >>= 1) vs += __shfl_xor(vs, off);
  if ((t & 63) == 0) w2[t >> 6] = vs;
  __syncthreads();
  const float var = (w2[0] + w2[1] + w2[2] + w2[3]) * (1.f / DIMSZ);
  const float rstd = rsqrtf(var + 1e-5f);

#pragma unroll
  for (int i = 0; i < 4; i++) {
    const int c = t + i * 256;
    out[base + c] = (x[i] - mean) * rstd * gamma[c] + beta[c];
  }
}

// ---------------------------------------------------------------------------
extern "C" void kernel_launch(void* const* d_in, const int* in_sizes, int n_in,
                              void* d_out, int out_size, void* d_ws,
                              size_t ws_size, hipStream_t stream) {
  const float* query = (const float*)d_in[0];
  const float* key   = (const float*)d_in[1];
  const float* value = (const float*)d_in[2];
  const float* Wq = (const float*)d_in[3];
  const float* bq = (const float*)d_in[4];
  const float* Wk = (const float*)d_in[5];
  const float* bk = (const float*)d_in[6];
  const float* Wv = (const float*)d_in[7];
  const float* bv = (const float*)d_in[8];
  const float* Wo = (const float*)d_in[9];
  const float* bo = (const float*)d_in[10];
  const float* ln_gamma = (const float*)d_in[11];
  const float* ln_beta  = (const float*)d_in[12];

  float* out  = (float*)d_out;                          // [B, Tq, DIM]
  float* attn = out + (long)BATCH * TQ * DIMSZ;         // [B, H, Tq, Tk]

  float* ws = (float*)d_ws;
  float* qbuf = ws;                                     // [B*Tq, DIM]  8 MB
  float* kbuf = qbuf + (long)BATCH * TQ * DIMSZ;        // [B*Tk, DIM] 32 MB
  float* vbuf = kbuf + (long)BATCH * TK * DIMSZ;        // [B*Tk, DIM] 32 MB
  float* aout = vbuf + (long)BATCH * TK * DIMSZ;        // [B*Tq, DIM]  8 MB
  float* ybuf = aout + (long)BATCH * TQ * DIMSZ;        // [B*Tq, DIM]  8 MB

  const int Mq = BATCH * TQ;   // 2048
  const int Mk = BATCH * TK;   // 8192

  // Projections
  gemm_nt_bias<<<dim3(DIMSZ / 64, Mq / 64), 256, 0, stream>>>(
      query, Wq, bq, qbuf, Mq, DIMSZ, DIMSZ);
  gemm_nt_bias<<<dim3(DIMSZ / 64, Mk / 64), 256, 0, stream>>>(
      key, Wk, bk, kbuf, Mk, DIMSZ, DIMSZ);
  gemm_nt_bias<<<dim3(DIMSZ / 64, Mk / 64), 256, 0, stream>>>(
      value, Wv, bv, vbuf, Mk, DIMSZ, DIMSZ);

  // Scores -> attn region (pre-softmax)
  scores_gemm<<<dim3(TK / 64, TQ / 64, BATCH * NH), 256, 0, stream>>>(
      qbuf, kbuf, attn);

  // Softmax in place (this materializes output 1)
  softmax_rows<<<dim3(BATCH * NH * TQ), 256, 0, stream>>>(attn);

  // PV
  pv_gemm<<<dim3(1, TQ / 64, BATCH * NH), 256, 0, stream>>>(attn, vbuf, aout);

  // Output projection
  gemm_nt_bias<<<dim3(DIMSZ / 64, Mq / 64), 256, 0, stream>>>(
      aout, Wo, bo, ybuf, Mq, DIMSZ, DIMSZ);

  // Residual + LayerNorm -> output 0
  residual_ln<<<dim3(Mq), 256, 0, stream>>>(query, ybuf, ln_gamma, ln_beta,
                                            out);
}

// Round 2
// 742.343 us; speedup vs baseline: 2.5327x; 2.5327x over previous
//
#include <hip/hip_runtime.h>
#include <hip/hip_bf16.h>

// B=2, Tq=1024, Tk=4096, DIM=1024, H=16, Hd=64, SCALE=0.125
#define BATCH 2
#define TQ 1024
#define TK 4096
#define DIMSZ 1024
#define NH 16
#define HD 64
#define SCALE 0.125f

typedef __bf16 bf16x8 __attribute__((ext_vector_type(8)));
typedef float f32x4 __attribute__((ext_vector_type(4)));

static __device__ inline unsigned short f2bf(float x) {
  unsigned int u = __float_as_uint(x);
  unsigned int r = (u + 0x7fffu + ((u >> 16) & 1u)) >> 16;
  return (unsigned short)r;
}
static __device__ inline unsigned int pack2(float a, float b) {
  return (unsigned int)f2bf(a) | ((unsigned int)f2bf(b) << 16);
}

// ---------------------------------------------------------------------------
// cast f32 -> bf16 (packed ushort), n multiple of 4
// ---------------------------------------------------------------------------
__global__ __launch_bounds__(256) void cast_bf16(const float* __restrict__ in,
                                                 unsigned short* __restrict__ out,
                                                 long n) {
  long stride = (long)gridDim.x * 256 * 4;
  for (long i = ((long)blockIdx.x * 256 + threadIdx.x) * 4; i < n; i += stride) {
    float4 v = *(const float4*)&in[i];
    uint2 o;
    o.x = pack2(v.x, v.y);
    o.y = pack2(v.z, v.w);
    *(uint2*)&out[i] = o;
  }
}

// ---------------------------------------------------------------------------
// bf16 MFMA GEMM-NT: C[m,n] = sum_k A[m,k]*B[n,k] + bias[n]
// A[M,K], B[N,K] bf16 row-major. M,N mult of 128, K mult of 32.
// 256 thr = 4 waves (2x2), 128x128 tile, BK=32; padded LDS rows (40 bf16).
// ---------------------------------------------------------------------------
template <bool OUT_BF16>
__global__ __launch_bounds__(256) void gemm_nt_mfma(
    const unsigned short* __restrict__ A, const unsigned short* __restrict__ B,
    const float* __restrict__ bias, void* __restrict__ Cout,
    int M, int N, int K) {
  __shared__ unsigned short As[128][40];
  __shared__ unsigned short Bs[128][40];
  const int t = threadIdx.x;
  const int lane = t & 63, wid = t >> 6;
  const int wm = wid >> 1, wn = wid & 1;
  const int l15 = lane & 15, l4 = lane >> 4;
  const int row0 = blockIdx.y * 128, col0 = blockIdx.x * 128;

  f32x4 acc[4][4];
#pragma unroll
  for (int i = 0; i < 4; i++)
#pragma unroll
    for (int j = 0; j < 4; j++) acc[i][j] = (f32x4){0.f, 0.f, 0.f, 0.f};

  for (int k0 = 0; k0 < K; k0 += 32) {
#pragma unroll
    for (int p = 0; p < 2; p++) {
      const int c = t + p * 256;
      const int r = c >> 2, kc = c & 3;
      *(uint4*)&As[r][kc * 8] =
          *(const uint4*)&A[(size_t)(row0 + r) * K + k0 + kc * 8];
      *(uint4*)&Bs[r][kc * 8] =
          *(const uint4*)&B[(size_t)(col0 + r) * K + k0 + kc * 8];
    }
    __syncthreads();
    bf16x8 av[4], bv[4];
#pragma unroll
    for (int f = 0; f < 4; f++) {
      av[f] = *(const bf16x8*)&As[wm * 64 + f * 16 + l15][l4 * 8];
      bv[f] = *(const bf16x8*)&Bs[wn * 64 + f * 16 + l15][l4 * 8];
    }
#pragma unroll
    for (int fm = 0; fm < 4; fm++)
#pragma unroll
      for (int fn = 0; fn < 4; fn++)
        acc[fm][fn] = __builtin_amdgcn_mfma_f32_16x16x32_bf16(
            av[fm], bv[fn], acc[fm][fn], 0, 0, 0);
    __syncthreads();
  }

#pragma unroll
  for (int fm = 0; fm < 4; fm++) {
#pragma unroll
    for (int i = 0; i < 4; i++) {
      const int rr = row0 + wm * 64 + fm * 16 + l4 * 4 + i;
#pragma unroll
      for (int fn = 0; fn < 4; fn++) {
        const int c = col0 + wn * 64 + fn * 16 + l15;
        const float val = acc[fm][fn][i] + bias[c];
        if (OUT_BF16)
          ((unsigned short*)Cout)[(size_t)rr * N + c] = f2bf(val);
        else
          ((float*)Cout)[(size_t)rr * N + c] = val;
      }
    }
  }
}

// ---------------------------------------------------------------------------
// Scores: attn_raw[z,m,n] = SCALE * sum_d q[b,m,h*64+d]*k[b,n,h*64+d], f32 out
// z = b*16+h. bf16 MFMA NT with lda=ldb=DIMSZ, K=64.
// ---------------------------------------------------------------------------
__global__ __launch_bounds__(256) void scores_mfma(
    const unsigned short* __restrict__ qb, const unsigned short* __restrict__ kb,
    float* __restrict__ attn) {
  const int z = blockIdx.z, b = z >> 4, h = z & 15;
  const unsigned short* A = qb + (size_t)b * TQ * DIMSZ + h * HD;
  const unsigned short* B = kb + (size_t)b * TK * DIMSZ + h * HD;
  float* C = attn + (size_t)z * TQ * TK;

  __shared__ unsigned short As[128][40];
  __shared__ unsigned short Bs[128][40];
  const int t = threadIdx.x;
  const int lane = t & 63, wid = t >> 6;
  const int wm = wid >> 1, wn = wid & 1;
  const int l15 = lane & 15, l4 = lane >> 4;
  const int row0 = blockIdx.y * 128, col0 = blockIdx.x * 128;

  f32x4 acc[4][4];
#pragma unroll
  for (int i = 0; i < 4; i++)
#pragma unroll
    for (int j = 0; j < 4; j++) acc[i][j] = (f32x4){0.f, 0.f, 0.f, 0.f};

  for (int k0 = 0; k0 < HD; k0 += 32) {
#pragma unroll
    for (int p = 0; p < 2; p++) {
      const int c = t + p * 256;
      const int r = c >> 2, kc = c & 3;
      *(uint4*)&As[r][kc * 8] =
          *(const uint4*)&A[(size_t)(row0 + r) * DIMSZ + k0 + kc * 8];
      *(uint4*)&Bs[r][kc * 8] =
          *(const uint4*)&B[(size_t)(col0 + r) * DIMSZ + k0 + kc * 8];
    }
    __syncthreads();
    bf16x8 av[4], bv[4];
#pragma unroll
    for (int f = 0; f < 4; f++) {
      av[f] = *(const bf16x8*)&As[wm * 64 + f * 16 + l15][l4 * 8];
      bv[f] = *(const bf16x8*)&Bs[wn * 64 + f * 16 + l15][l4 * 8];
    }
#pragma unroll
    for (int fm = 0; fm < 4; fm++)
#pragma unroll
      for (int fn = 0; fn < 4; fn++)
        acc[fm][fn] = __builtin_amdgcn_mfma_f32_16x16x32_bf16(
            av[fm], bv[fn], acc[fm][fn], 0, 0, 0);
    __syncthreads();
  }

#pragma unroll
  for (int fm = 0; fm < 4; fm++)
#pragma unroll
    for (int i = 0; i < 4; i++) {
      const int rr = row0 + wm * 64 + fm * 16 + l4 * 4 + i;
#pragma unroll
      for (int fn = 0; fn < 4; fn++) {
        const int c = col0 + wn * 64 + fn * 16 + l15;
        C[(size_t)rr * TK + c] = SCALE * acc[fm][fn][i];
      }
    }
}

// ---------------------------------------------------------------------------
// Per-row max and 1/sum(exp(s-max)) over Tk=4096. One block per row.
// ---------------------------------------------------------------------------
__global__ __launch_bounds__(256) void row_stats(const float* __restrict__ attn,
                                                 float2* __restrict__ stats) {
  __shared__ float wred[4];
  const size_t base = (size_t)blockIdx.x * TK;
  const int t = threadIdx.x;

  float4 v[4];
#pragma unroll
  for (int p = 0; p < 4; p++)
    v[p] = *(const float4*)&attn[base + (size_t)(t + p * 256) * 4];

  float lmax = -1e30f;
#pragma unroll
  for (int p = 0; p < 4; p++)
    lmax = fmaxf(fmaxf(fmaxf(lmax, v[p].x), fmaxf(v[p].y, v[p].z)), v[p].w);
#pragma unroll
  for (int off = 32; off; off >>= 1) lmax = fmaxf(lmax, __shfl_xor(lmax, off));
  if ((t & 63) == 0) wred[t >> 6] = lmax;
  __syncthreads();
  const float rmax = fmaxf(fmaxf(wred[0], wred[1]), fmaxf(wred[2], wred[3]));
  __syncthreads();

  float lsum = 0.f;
#pragma unroll
  for (int p = 0; p < 4; p++) {
    lsum += __expf(v[p].x - rmax) + __expf(v[p].y - rmax) +
            __expf(v[p].z - rmax) + __expf(v[p].w - rmax);
  }
#pragma unroll
  for (int off = 32; off; off >>= 1) lsum += __shfl_xor(lsum, off);
  if ((t & 63) == 0) wred[t >> 6] = lsum;
  __syncthreads();
  const float rsum = wred[0] + wred[1] + wred[2] + wred[3];
  if (t == 0) stats[blockIdx.x] = make_float2(rmax, 1.f / rsum);
}

// ---------------------------------------------------------------------------
// Transpose V head-slices: vT[z*64+d][k] = vb[b*TK+k][h*64+d], bf16.
// ---------------------------------------------------------------------------
__global__ __launch_bounds__(256) void transpose_v(
    const unsigned short* __restrict__ vb, unsigned short* __restrict__ vT) {
  const int z = blockIdx.z, b = z >> 4, h = z & 15;
  const int k0 = blockIdx.x * 64;
  __shared__ unsigned short Ts[64][68];
  const int t = threadIdx.x;
  const int c4 = (t & 15) * 4, r = t >> 4;
#pragma unroll
  for (int p = 0; p < 4; p++) {
    const int rr = r + p * 16;
    *(uint2*)&Ts[rr][c4] =
        *(const uint2*)&vb[(size_t)(b * TK + k0 + rr) * DIMSZ + h * HD + c4];
  }
  __syncthreads();
#pragma unroll
  for (int p = 0; p < 4; p++) {
    const int c2 = t + p * 256;
    const int d = c2 >> 4, k4 = (c2 & 15) * 4;
    uint2 o;
    o.x = (unsigned int)Ts[k4][d] | ((unsigned int)Ts[k4 + 1][d] << 16);
    o.y = (unsigned int)Ts[k4 + 2][d] | ((unsigned int)Ts[k4 + 3][d] << 16);
    *(uint2*)&vT[(size_t)(z * HD + d) * TK + k0 + k4] = o;
  }
}

// ---------------------------------------------------------------------------
// Fused: read raw scores, p = exp(s-max)*inv, write normalized attn in place,
// and O = P @ vT^T via bf16 MFMA. BM=64, BN=64, BK=32, 4 waves (2x2).
// ---------------------------------------------------------------------------
__global__ __launch_bounds__(256) void pv_fused(
    float* __restrict__ attn, const float2* __restrict__ stats,
    const unsigned short* __restrict__ vT, unsigned short* __restrict__ aout) {
  const int z = blockIdx.z, b = z >> 4, h = z & 15;
  float* Araw = attn + (size_t)z * TQ * TK;
  const unsigned short* Bv = vT + (size_t)z * HD * TK;
  const int m0 = blockIdx.y * 64;

  __shared__ unsigned short As[64][40];
  __shared__ unsigned short Bs[64][40];
  __shared__ float rmax[64];
  __shared__ float rinv[64];

  const int t = threadIdx.x;
  const int lane = t & 63, wid = t >> 6;
  const int wm = wid >> 1, wn = wid & 1;
  const int l15 = lane & 15, l4 = lane >> 4;

  if (t < 64) {
    float2 s = stats[(size_t)z * TQ + m0 + t];
    rmax[t] = s.x;
    rinv[t] = s.y;
  }
  __syncthreads();

  f32x4 acc[2][2];
#pragma unroll
  for (int i = 0; i < 2; i++)
#pragma unroll
    for (int j = 0; j < 2; j++) acc[i][j] = (f32x4){0.f, 0.f, 0.f, 0.f};

  for (int k0 = 0; k0 < TK; k0 += 32) {
    // A stage: raw f32 -> p -> (global writeback f32) + (LDS bf16)
#pragma unroll
    for (int p = 0; p < 2; p++) {
      const int c = t + p * 256;
      const int r = c >> 3, kc = c & 7;
      float* gp = &Araw[(size_t)(m0 + r) * TK + k0 + kc * 4];
      float4 s4 = *(const float4*)gp;
      const float mx = rmax[r], iv = rinv[r];
      float p0 = __expf(s4.x - mx) * iv;
      float p1 = __expf(s4.y - mx) * iv;
      float p2 = __expf(s4.z - mx) * iv;
      float p3 = __expf(s4.w - mx) * iv;
      *(float4*)gp = make_float4(p0, p1, p2, p3);
      uint2 pb;
      pb.x = pack2(p0, p1);
      pb.y = pack2(p2, p3);
      *(uint2*)&As[r][kc * 4] = pb;
    }
    // B stage: vT tile [64 n][32 k]
    {
      const int n = t >> 2, kc = t & 3;
      *(uint4*)&Bs[n][kc * 8] =
          *(const uint4*)&Bv[(size_t)n * TK + k0 + kc * 8];
    }
    __syncthreads();
    bf16x8 av[2], bv2[2];
#pragma unroll
    for (int f = 0; f < 2; f++) {
      av[f] = *(const bf16x8*)&As[wm * 32 + f * 16 + l15][l4 * 8];
      bv2[f] = *(const bf16x8*)&Bs[wn * 32 + f * 16 + l15][l4 * 8];
    }
#pragma unroll
    for (int fm = 0; fm < 2; fm++)
#pragma unroll
      for (int fn = 0; fn < 2; fn++)
        acc[fm][fn] = __builtin_amdgcn_mfma_f32_16x16x32_bf16(
            av[fm], bv2[fn], acc[fm][fn], 0, 0, 0);
    __syncthreads();
  }

#pragma unroll
  for (int fm = 0; fm < 2; fm++)
#pragma unroll
    for (int i = 0; i < 4; i++) {
      const int rr = m0 + wm * 32 + fm * 16 + l4 * 4 + i;
#pragma unroll
      for (int fn = 0; fn < 2; fn++) {
        const int c = wn * 32 + fn * 16 + l15;
        aout[(size_t)(b * TQ + rr) * DIMSZ + h * HD + c] = f2bf(acc[fm][fn][i]);
      }
    }
}

// ---------------------------------------------------------------------------
// Residual + LayerNorm (f32)
// ---------------------------------------------------------------------------
__global__ __launch_bounds__(256) void residual_ln(
    const float* __restrict__ q, const float* __restrict__ y,
    const float* __restrict__ gamma, const float* __restrict__ beta,
    float* __restrict__ out) {
  __shared__ float w1[4];
  __shared__ float w2[4];
  const size_t base = (size_t)blockIdx.x * DIMSZ;
  const int t = threadIdx.x;

  float x[4];
  float s = 0.f;
#pragma unroll
  for (int i = 0; i < 4; i++) {
    const int c = t + i * 256;
    x[i] = q[base + c] + y[base + c];
    s += x[i];
  }
#pragma unroll
  for (int off = 32; off; off >>= 1) s += __shfl_xor(s, off);
  if ((t & 63) == 0) w1[t >> 6] = s;
  __syncthreads();
  const float mean = (w1[0] + w1[1] + w1[2] + w1[3]) * (1.f / DIMSZ);

  float vs = 0.f;
#pragma unroll
  for (int i = 0; i < 4; i++) {
    const float d = x[i] - mean;
    vs += d * d;
  }
#pragma unroll
  for (int off = 32; off; off >>= 1) vs += __shfl_xor(vs, off);
  if ((t & 63) == 0) w2[t >> 6] = vs;
  __syncthreads();
  const float var = (w2[0] + w2[1] + w2[2] + w2[3]) * (1.f / DIMSZ);
  const float rstd = rsqrtf(var + 1e-5f);

#pragma unroll
  for (int i = 0; i < 4; i++) {
    const int c = t + i * 256;
    out[base + c] = (x[i] - mean) * rstd * gamma[c] + beta[c];
  }
}

// ---------------------------------------------------------------------------
extern "C" void kernel_launch(void* const* d_in, const int* in_sizes, int n_in,
                              void* d_out, int out_size, void* d_ws,
                              size_t ws_size, hipStream_t stream) {
  const float* query = (const float*)d_in[0];
  const float* key   = (const float*)d_in[1];
  const float* value = (const float*)d_in[2];
  const float* Wq = (const float*)d_in[3];
  const float* bq = (const float*)d_in[4];
  const float* Wk = (const float*)d_in[5];
  const float* bk = (const float*)d_in[6];
  const float* Wv = (const float*)d_in[7];
  const float* bv = (const float*)d_in[8];
  const float* Wo = (const float*)d_in[9];
  const float* bo = (const float*)d_in[10];
  const float* ln_gamma = (const float*)d_in[11];
  const float* ln_beta  = (const float*)d_in[12];

  float* out  = (float*)d_out;                   // [B, Tq, DIM] f32
  float* attn = out + (size_t)BATCH * TQ * DIMSZ;// [32, 1024, 4096] f32

  const size_t MQ = (size_t)BATCH * TQ * DIMSZ;  // 2M elems
  const size_t MK = (size_t)BATCH * TK * DIMSZ;  // 8M elems

  unsigned short* ws = (unsigned short*)d_ws;
  unsigned short* qb = ws;              // 2M bf16 (4 MB)
  unsigned short* kb = qb + MQ;         // 8M (16 MB)
  unsigned short* vb = kb + MK;         // 8M (16 MB)
  unsigned short* vT = vb + MK;         // 8M (16 MB)
  unsigned short* ab = vT + MK;         // 2M (4 MB)
  float* ybuf = (float*)(ab + MQ);      // 2M f32 (8 MB)
  float2* stats = (float2*)(ybuf + MQ); // 32K float2 (256 KB)
  unsigned short* scrIn = (unsigned short*)(stats + (size_t)BATCH * NH * TQ);
  unsigned short* scrW = scrIn + MK;    // weights scratch (2 MB)

  const dim3 blk(256);

  // ---- Q projection ----
  cast_bf16<<<2048, blk, 0, stream>>>(query, scrIn, (long)MQ);
  cast_bf16<<<1024, blk, 0, stream>>>(Wq, scrW, (long)DIMSZ * DIMSZ);
  gemm_nt_mfma<true><<<dim3(DIMSZ / 128, (BATCH * TQ) / 128), blk, 0, stream>>>(
      scrIn, scrW, bq, qb, BATCH * TQ, DIMSZ, DIMSZ);
  // ---- K projection ----
  cast_bf16<<<2048, blk, 0, stream>>>(key, scrIn, (long)MK);
  cast_bf16<<<1024, blk, 0, stream>>>(Wk, scrW, (long)DIMSZ * DIMSZ);
  gemm_nt_mfma<true><<<dim3(DIMSZ / 128, (BATCH * TK) / 128), blk, 0, stream>>>(
      scrIn, scrW, bk, kb, BATCH * TK, DIMSZ, DIMSZ);
  // ---- V projection ----
  cast_bf16<<<2048, blk, 0, stream>>>(value, scrIn, (long)MK);
  cast_bf16<<<1024, blk, 0, stream>>>(Wv, scrW, (long)DIMSZ * DIMSZ);
  gemm_nt_mfma<true><<<dim3(DIMSZ / 128, (BATCH * TK) / 128), blk, 0, stream>>>(
      scrIn, scrW, bv, vb, BATCH * TK, DIMSZ, DIMSZ);

  // ---- V transpose to [z][64][4096] ----
  transpose_v<<<dim3(TK / 64, 1, BATCH * NH), blk, 0, stream>>>(vb, vT);

  // ---- Scores (raw f32) ----
  scores_mfma<<<dim3(TK / 128, TQ / 128, BATCH * NH), blk, 0, stream>>>(
      qb, kb, attn);

  // ---- Row stats ----
  row_stats<<<dim3(BATCH * NH * TQ), blk, 0, stream>>>(attn, stats);

  // ---- Fused normalize + attn write + PV ----
  pv_fused<<<dim3(1, TQ / 64, BATCH * NH), blk, 0, stream>>>(attn, stats, vT,
                                                             ab);

  // ---- Output projection (f32 out) ----
  cast_bf16<<<1024, blk, 0, stream>>>(Wo, scrW, (long)DIMSZ * DIMSZ);
  gemm_nt_mfma<false><<<dim3(DIMSZ / 128, (BATCH * TQ) / 128), blk, 0, stream>>>(
      ab, scrW, bo, ybuf, BATCH * TQ, DIMSZ, DIMSZ);

  // ---- Residual + LayerNorm ----
  residual_ln<<<dim3(BATCH * TQ), blk, 0, stream>>>(query, ybuf, ln_gamma,
                                                    ln_beta, out);
}

// Round 3
// 454.080 us; speedup vs baseline: 4.1405x; 1.6348x over previous
//
#include <hip/hip_runtime.h>
#include <hip/hip_bf16.h>

// B=2, Tq=1024, Tk=4096, DIM=1024, H=16, Hd=64, SCALE=0.125
#define BATCH 2
#define TQ 1024
#define TK 4096
#define DIMSZ 1024
#define NH 16
#define HD 64
#define SCALE 0.125f

typedef __bf16 bf16x8 __attribute__((ext_vector_type(8)));
typedef float f32x4 __attribute__((ext_vector_type(4)));

static __device__ inline unsigned short f2bf(float x) {
  unsigned int u = __float_as_uint(x);
  unsigned int r = (u + 0x7fffu + ((u >> 16) & 1u)) >> 16;
  return (unsigned short)r;
}
static __device__ inline unsigned int pack2(float a, float b) {
  return (unsigned int)f2bf(a) | ((unsigned int)f2bf(b) << 16);
}

// ---------------------------------------------------------------------------
// Projection GEMM-NT with fused input cast: C[m,n] = sum_k A[m,k]*B[n,k]+bias
// A: f32 or bf16 [M,K]; B: f32 weights [N,K] (cast to bf16 in staging).
// 128x128 tile, BK=32, 4 waves (2x2). Out bf16 or f32.
// ---------------------------------------------------------------------------
template <bool A_BF16, bool OUT_BF16>
__global__ __launch_bounds__(256) void gemm_proj(
    const void* __restrict__ Ain, const float* __restrict__ Bf,
    const float* __restrict__ bias, void* __restrict__ Cout,
    int M, int N, int K) {
  __shared__ unsigned short As[128][40];
  __shared__ unsigned short Bs[128][40];
  const int t = threadIdx.x;
  const int lane = t & 63, wid = t >> 6;
  const int wm = wid >> 1, wn = wid & 1;
  const int l15 = lane & 15, l4 = lane >> 4;
  const int row0 = blockIdx.y * 128, col0 = blockIdx.x * 128;

  f32x4 acc[4][4];
#pragma unroll
  for (int i = 0; i < 4; i++)
#pragma unroll
    for (int j = 0; j < 4; j++) acc[i][j] = (f32x4){0.f, 0.f, 0.f, 0.f};

  for (int k0 = 0; k0 < K; k0 += 32) {
#pragma unroll
    for (int p = 0; p < 2; p++) {
      const int idx = t + p * 256;
      const int r = idx >> 2, kc = idx & 3;
      if (A_BF16) {
        *(uint4*)&As[r][kc * 8] = *(const uint4*)&(
            (const unsigned short*)Ain)[(size_t)(row0 + r) * K + k0 + kc * 8];
      } else {
        const float* Af = (const float*)Ain;
        const float4 v0 = *(const float4*)&Af[(size_t)(row0 + r) * K + k0 + kc * 8];
        const float4 v1 = *(const float4*)&Af[(size_t)(row0 + r) * K + k0 + kc * 8 + 4];
        uint4 w;
        w.x = pack2(v0.x, v0.y);
        w.y = pack2(v0.z, v0.w);
        w.z = pack2(v1.x, v1.y);
        w.w = pack2(v1.z, v1.w);
        *(uint4*)&As[r][kc * 8] = w;
      }
      {
        const float4 u0 = *(const float4*)&Bf[(size_t)(col0 + r) * K + k0 + kc * 8];
        const float4 u1 = *(const float4*)&Bf[(size_t)(col0 + r) * K + k0 + kc * 8 + 4];
        uint4 w;
        w.x = pack2(u0.x, u0.y);
        w.y = pack2(u0.z, u0.w);
        w.z = pack2(u1.x, u1.y);
        w.w = pack2(u1.z, u1.w);
        *(uint4*)&Bs[r][kc * 8] = w;
      }
    }
    __syncthreads();
    bf16x8 av[4], bv[4];
#pragma unroll
    for (int f = 0; f < 4; f++) {
      av[f] = *(const bf16x8*)&As[wm * 64 + f * 16 + l15][l4 * 8];
      bv[f] = *(const bf16x8*)&Bs[wn * 64 + f * 16 + l15][l4 * 8];
    }
#pragma unroll
    for (int fm = 0; fm < 4; fm++)
#pragma unroll
      for (int fn = 0; fn < 4; fn++)
        acc[fm][fn] = __builtin_amdgcn_mfma_f32_16x16x32_bf16(
            av[fm], bv[fn], acc[fm][fn], 0, 0, 0);
    __syncthreads();
  }

#pragma unroll
  for (int fm = 0; fm < 4; fm++) {
#pragma unroll
    for (int i = 0; i < 4; i++) {
      const int rr = row0 + wm * 64 + fm * 16 + l4 * 4 + i;
#pragma unroll
      for (int fn = 0; fn < 4; fn++) {
        const int c = col0 + wn * 64 + fn * 16 + l15;
        const float val = acc[fm][fn][i] + bias[c];
        if (OUT_BF16)
          ((unsigned short*)Cout)[(size_t)rr * N + c] = f2bf(val);
        else
          ((float*)Cout)[(size_t)rr * N + c] = val;
      }
    }
  }
}

// ---------------------------------------------------------------------------
// Transpose V head-slices: vT[z*64+d][k] = vb[b*TK+k][h*64+d], bf16.
// ---------------------------------------------------------------------------
__global__ __launch_bounds__(256) void transpose_v(
    const unsigned short* __restrict__ vb, unsigned short* __restrict__ vT) {
  const int z = blockIdx.z, b = z >> 4, h = z & 15;
  const int k0 = blockIdx.x * 64;
  __shared__ unsigned short Ts[64][68];
  const int t = threadIdx.x;
  const int c4 = (t & 15) * 4, r = t >> 4;
#pragma unroll
  for (int p = 0; p < 4; p++) {
    const int rr = r + p * 16;
    *(uint2*)&Ts[rr][c4] =
        *(const uint2*)&vb[(size_t)(b * TK + k0 + rr) * DIMSZ + h * HD + c4];
  }
  __syncthreads();
#pragma unroll
  for (int p = 0; p < 4; p++) {
    const int c2 = t + p * 256;
    const int d = c2 >> 4, k4 = (c2 & 15) * 4;
    uint2 o;
    o.x = (unsigned int)Ts[k4][d] | ((unsigned int)Ts[k4 + 1][d] << 16);
    o.y = (unsigned int)Ts[k4 + 2][d] | ((unsigned int)Ts[k4 + 3][d] << 16);
    *(uint2*)&vT[(size_t)(z * HD + d) * TK + k0 + k4] = o;
  }
}

// ---------------------------------------------------------------------------
// Pass A: per-row 1/sum(exp(SCALE*s)) with S recomputed by MFMA, no S write.
// BM=128 q-rows per block x full Tk. Grid (Tq/128, B*H).
// ---------------------------------------------------------------------------
__global__ __launch_bounds__(256) void attn_stats(
    const unsigned short* __restrict__ qb, const unsigned short* __restrict__ kb,
    float* __restrict__ inv_out) {
  const int z = blockIdx.y, b = z >> 4, h = z & 15;
  const int m0 = blockIdx.x * 128;
  __shared__ unsigned short Qs[128][72];
  __shared__ unsigned short Ks[128][72];
  __shared__ float partial[128][2];

  const int t = threadIdx.x;
  const int lane = t & 63, wid = t >> 6;
  const int wm = wid >> 1, wn = wid & 1;
  const int l15 = lane & 15, l4 = lane >> 4;

  // stage Q [128][64]
#pragma unroll
  for (int p = 0; p < 4; p++) {
    const int idx = t + p * 256;
    const int r = idx >> 3, kc = idx & 7;
    *(uint4*)&Qs[r][kc * 8] =
        *(const uint4*)&qb[(size_t)(b * TQ + m0 + r) * DIMSZ + h * HD + kc * 8];
  }
  __syncthreads();
  bf16x8 aq[4][2];
#pragma unroll
  for (int fm = 0; fm < 4; fm++)
#pragma unroll
    for (int ks = 0; ks < 2; ks++)
      aq[fm][ks] = *(const bf16x8*)&Qs[wm * 64 + fm * 16 + l15][ks * 32 + l4 * 8];

  float rsum[16];
#pragma unroll
  for (int r = 0; r < 16; r++) rsum[r] = 0.f;

  for (int kt = 0; kt < TK / 128; kt++) {
    __syncthreads();
#pragma unroll
    for (int p = 0; p < 4; p++) {
      const int idx = t + p * 256;
      const int r = idx >> 3, kc = idx & 7;
      *(uint4*)&Ks[r][kc * 8] = *(const uint4*)&kb[
          (size_t)(b * TK + kt * 128 + r) * DIMSZ + h * HD + kc * 8];
    }
    __syncthreads();
    bf16x8 bk_[4][2];
#pragma unroll
    for (int fn = 0; fn < 4; fn++)
#pragma unroll
      for (int ks = 0; ks < 2; ks++)
        bk_[fn][ks] =
            *(const bf16x8*)&Ks[wn * 64 + fn * 16 + l15][ks * 32 + l4 * 8];

    f32x4 acc[4][4];
#pragma unroll
    for (int i = 0; i < 4; i++)
#pragma unroll
      for (int j = 0; j < 4; j++) acc[i][j] = (f32x4){0.f, 0.f, 0.f, 0.f};
#pragma unroll
    for (int ks = 0; ks < 2; ks++)
#pragma unroll
      for (int fm = 0; fm < 4; fm++)
#pragma unroll
        for (int fn = 0; fn < 4; fn++)
          acc[fm][fn] = __builtin_amdgcn_mfma_f32_16x16x32_bf16(
              aq[fm][ks], bk_[fn][ks], acc[fm][fn], 0, 0, 0);

#pragma unroll
    for (int fm = 0; fm < 4; fm++)
#pragma unroll
      for (int i = 0; i < 4; i++) {
        float s = 0.f;
#pragma unroll
        for (int fn = 0; fn < 4; fn++) s += __expf(acc[fm][fn][i] * SCALE);
        rsum[fm * 4 + i] += s;
      }
  }

#pragma unroll
  for (int off = 1; off < 16; off <<= 1)
#pragma unroll
    for (int r = 0; r < 16; r++) rsum[r] += __shfl_xor(rsum[r], off);

  if (l15 == 0) {
#pragma unroll
    for (int fm = 0; fm < 4; fm++)
#pragma unroll
      for (int i = 0; i < 4; i++)
        partial[wm * 64 + fm * 16 + l4 * 4 + i][wn] = rsum[fm * 4 + i];
  }
  __syncthreads();
  if (t < 128)
    inv_out[(size_t)z * TQ + m0 + t] = 1.f / (partial[t][0] + partial[t][1]);
}

// ---------------------------------------------------------------------------
// Pass B: recompute S, normalize, write attn f32 (the only attn traffic),
// and O = P @ V via LDS-routed bf16 P. BM=64 rows x BN=128 k-cols per iter.
// ---------------------------------------------------------------------------
__global__ __launch_bounds__(256) void attn_pv(
    const unsigned short* __restrict__ qb, const unsigned short* __restrict__ kb,
    const unsigned short* __restrict__ vT, const float* __restrict__ inv_in,
    float* __restrict__ attn, unsigned short* __restrict__ aout) {
  const int z = blockIdx.y, b = z >> 4, h = z & 15;
  const int m0 = blockIdx.x * 64;
  __shared__ unsigned short Qs[64][72];
  __shared__ unsigned short Ks[128][72];
  __shared__ unsigned short Ps[64][140];
  __shared__ unsigned short Vs[64][140];
  __shared__ float rinv[64];

  const int t = threadIdx.x;
  const int lane = t & 63, wid = t >> 6;
  const int wm = wid >> 1, wn = wid & 1;
  const int l15 = lane & 15, l4 = lane >> 4;

  // stage Q [64][64]
#pragma unroll
  for (int p = 0; p < 2; p++) {
    const int idx = t + p * 256;
    const int r = idx >> 3, kc = idx & 7;
    *(uint4*)&Qs[r][kc * 8] =
        *(const uint4*)&qb[(size_t)(b * TQ + m0 + r) * DIMSZ + h * HD + kc * 8];
  }
  if (t < 64) rinv[t] = inv_in[(size_t)z * TQ + m0 + t];
  __syncthreads();
  bf16x8 aq[2][2];
#pragma unroll
  for (int fm = 0; fm < 2; fm++)
#pragma unroll
    for (int ks = 0; ks < 2; ks++)
      aq[fm][ks] = *(const bf16x8*)&Qs[wm * 32 + fm * 16 + l15][ks * 32 + l4 * 8];

  f32x4 acc_o[4];
#pragma unroll
  for (int j = 0; j < 4; j++) acc_o[j] = (f32x4){0.f, 0.f, 0.f, 0.f};

  float* attn_z = attn + (size_t)z * TQ * TK;

  for (int kt = 0; kt < TK / 128; kt++) {
    __syncthreads();
    // stage K tile [128 k-rows][64 d]
#pragma unroll
    for (int p = 0; p < 4; p++) {
      const int idx = t + p * 256;
      const int r = idx >> 3, kc = idx & 7;
      *(uint4*)&Ks[r][kc * 8] = *(const uint4*)&kb[
          (size_t)(b * TK + kt * 128 + r) * DIMSZ + h * HD + kc * 8];
    }
    // stage V tile [64 d][128 k]
#pragma unroll
    for (int p = 0; p < 4; p++) {
      const int idx = t + p * 256;
      const int d = idx >> 4, kc = idx & 15;
      *(uint4*)&Vs[d][kc * 8] =
          *(const uint4*)&vT[(size_t)(z * HD + d) * TK + kt * 128 + kc * 8];
    }
    __syncthreads();

    // S tile [64][128]
    bf16x8 bk_[4][2];
#pragma unroll
    for (int fn = 0; fn < 4; fn++)
#pragma unroll
      for (int ks = 0; ks < 2; ks++)
        bk_[fn][ks] =
            *(const bf16x8*)&Ks[wn * 64 + fn * 16 + l15][ks * 32 + l4 * 8];
    f32x4 acc_s[2][4];
#pragma unroll
    for (int i = 0; i < 2; i++)
#pragma unroll
      for (int j = 0; j < 4; j++) acc_s[i][j] = (f32x4){0.f, 0.f, 0.f, 0.f};
#pragma unroll
    for (int ks = 0; ks < 2; ks++)
#pragma unroll
      for (int fm = 0; fm < 2; fm++)
#pragma unroll
        for (int fn = 0; fn < 4; fn++)
          acc_s[fm][fn] = __builtin_amdgcn_mfma_f32_16x16x32_bf16(
              aq[fm][ks], bk_[fn][ks], acc_s[fm][fn], 0, 0, 0);

    // normalize + write attn + park bf16 P in LDS
#pragma unroll
    for (int fm = 0; fm < 2; fm++)
#pragma unroll
      for (int i = 0; i < 4; i++) {
        const int row = wm * 32 + fm * 16 + l4 * 4 + i;
        const float iv = rinv[row];
        float* arow = &attn_z[(size_t)(m0 + row) * TK + kt * 128];
#pragma unroll
        for (int fn = 0; fn < 4; fn++) {
          const int col = wn * 64 + fn * 16 + l15;
          const float p = __expf(acc_s[fm][fn][i] * SCALE) * iv;
          arow[col] = p;
          Ps[row][col] = f2bf(p);
        }
      }
    __syncthreads();

    // O += P[64x128] @ V[128x64]
#pragma unroll
    for (int ks2 = 0; ks2 < 4; ks2++) {
      const bf16x8 ap =
          *(const bf16x8*)&Ps[wid * 16 + l15][ks2 * 32 + l4 * 8];
#pragma unroll
      for (int fn = 0; fn < 4; fn++) {
        const bf16x8 bvv =
            *(const bf16x8*)&Vs[fn * 16 + l15][ks2 * 32 + l4 * 8];
        acc_o[fn] = __builtin_amdgcn_mfma_f32_16x16x32_bf16(ap, bvv,
                                                            acc_o[fn], 0, 0, 0);
      }
    }
  }

#pragma unroll
  for (int fn = 0; fn < 4; fn++)
#pragma unroll
    for (int i = 0; i < 4; i++) {
      const int rr = m0 + wid * 16 + l4 * 4 + i;
      aout[(size_t)(b * TQ + rr) * DIMSZ + h * HD + fn * 16 + l15] =
          f2bf(acc_o[fn][i]);
    }
}

// ---------------------------------------------------------------------------
// Residual + LayerNorm (f32)
// ---------------------------------------------------------------------------
__global__ __launch_bounds__(256) void residual_ln(
    const float* __restrict__ q, const float* __restrict__ y,
    const float* __restrict__ gamma, const float* __restrict__ beta,
    float* __restrict__ out) {
  __shared__ float w1[4];
  __shared__ float w2[4];
  const size_t base = (size_t)blockIdx.x * DIMSZ;
  const int t = threadIdx.x;

  float x[4];
  float s = 0.f;
#pragma unroll
  for (int i = 0; i < 4; i++) {
    const int c = t + i * 256;
    x[i] = q[base + c] + y[base + c];
    s += x[i];
  }
#pragma unroll
  for (int off = 32; off; off >>= 1) s += __shfl_xor(s, off);
  if ((t & 63) == 0) w1[t >> 6] = s;
  __syncthreads();
  const float mean = (w1[0] + w1[1] + w1[2] + w1[3]) * (1.f / DIMSZ);

  float vs = 0.f;
#pragma unroll
  for (int i = 0; i < 4; i++) {
    const float d = x[i] - mean;
    vs += d * d;
  }
#pragma unroll
  for (int off = 32; off; off >>= 1) vs += __shfl_xor(vs, off);
  if ((t & 63) == 0) w2[t >> 6] = vs;
  __syncthreads();
  const float var = (w2[0] + w2[1] + w2[2] + w2[3]) * (1.f / DIMSZ);
  const float rstd = rsqrtf(var + 1e-5f);

#pragma unroll
  for (int i = 0; i < 4; i++) {
    const int c = t + i * 256;
    out[base + c] = (x[i] - mean) * rstd * gamma[c] + beta[c];
  }
}

// ---------------------------------------------------------------------------
extern "C" void kernel_launch(void* const* d_in, const int* in_sizes, int n_in,
                              void* d_out, int out_size, void* d_ws,
                              size_t ws_size, hipStream_t stream) {
  const float* query = (const float*)d_in[0];
  const float* key   = (const float*)d_in[1];
  const float* value = (const float*)d_in[2];
  const float* Wq = (const float*)d_in[3];
  const float* bq = (const float*)d_in[4];
  const float* Wk = (const float*)d_in[5];
  const float* bk = (const float*)d_in[6];
  const float* Wv = (const float*)d_in[7];
  const float* bv = (const float*)d_in[8];
  const float* Wo = (const float*)d_in[9];
  const float* bo = (const float*)d_in[10];
  const float* ln_gamma = (const float*)d_in[11];
  const float* ln_beta  = (const float*)d_in[12];

  float* out  = (float*)d_out;                    // [B, Tq, DIM] f32
  float* attn = out + (size_t)BATCH * TQ * DIMSZ; // [32, 1024, 4096] f32

  const size_t MQ = (size_t)BATCH * TQ * DIMSZ;   // 2M
  const size_t MK = (size_t)BATCH * TK * DIMSZ;   // 8M

  unsigned short* ws = (unsigned short*)d_ws;
  unsigned short* qb = ws;               // 4 MB
  unsigned short* kb = qb + MQ;          // 16 MB
  unsigned short* vb = kb + MK;          // 16 MB
  unsigned short* vT = vb + MK;          // 16 MB
  unsigned short* ab = vT + MK;          // 4 MB
  float* ybuf = (float*)(ab + MQ);       // 8 MB
  float* inv  = ybuf + MQ;               // 128 KB

  const dim3 blk(256);

  // Projections (fused f32->bf16 cast in staging)
  gemm_proj<false, true><<<dim3(DIMSZ / 128, (BATCH * TQ) / 128), blk, 0,
                           stream>>>(query, Wq, bq, qb, BATCH * TQ, DIMSZ,
                                     DIMSZ);
  gemm_proj<false, true><<<dim3(DIMSZ / 128, (BATCH * TK) / 128), blk, 0,
                           stream>>>(key, Wk, bk, kb, BATCH * TK, DIMSZ,
                                     DIMSZ);
  gemm_proj<false, true><<<dim3(DIMSZ / 128, (BATCH * TK) / 128), blk, 0,
                           stream>>>(value, Wv, bv, vb, BATCH * TK, DIMSZ,
                                     DIMSZ);

  transpose_v<<<dim3(TK / 64, 1, BATCH * NH), blk, 0, stream>>>(vb, vT);

  // Pass A: row sums (no score materialization)
  attn_stats<<<dim3(TQ / 128, BATCH * NH), blk, 0, stream>>>(qb, kb, inv);

  // Pass B: recompute scores, write normalized attn, PV
  attn_pv<<<dim3(TQ / 64, BATCH * NH), blk, 0, stream>>>(qb, kb, vT, inv,
                                                         attn, ab);

  // Output projection (bf16 A, f32 weights, f32 out)
  gemm_proj<true, false><<<dim3(DIMSZ / 128, (BATCH * TQ) / 128), blk, 0,
                           stream>>>(ab, Wo, bo, ybuf, BATCH * TQ, DIMSZ,
                                     DIMSZ);

  residual_ln<<<dim3(BATCH * TQ), blk, 0, stream>>>(query, ybuf, ln_gamma,
                                                    ln_beta, out);
}

// Round 5
// 397.097 us; speedup vs baseline: 4.7346x; 1.1435x over previous
//
#include <hip/hip_runtime.h>
#include <hip/hip_bf16.h>

// B=2, Tq=1024, Tk=4096, DIM=1024, H=16, Hd=64, SCALE=0.125
#define BATCH 2
#define TQ 1024
#define TK 4096
#define DIMSZ 1024
#define NH 16
#define HD 64
#define SCALE 0.125f

typedef __bf16 bf16x8 __attribute__((ext_vector_type(8)));
typedef float f32x4 __attribute__((ext_vector_type(4)));

static __device__ inline unsigned short f2bf(float x) {
  unsigned int u = __float_as_uint(x);
  unsigned int r = (u + 0x7fffu + ((u >> 16) & 1u)) >> 16;
  return (unsigned short)r;
}
static __device__ inline unsigned int pack2(float a, float b) {
  return (unsigned int)f2bf(a) | ((unsigned int)f2bf(b) << 16);
}

// ---------------------------------------------------------------------------
// Projection GEMM-NT with fused input cast: C[m,n] = sum_k A[m,k]*B[n,k]+bias
// A: f32 or bf16 [M,K]; B: f32 weights [N,K] (cast to bf16 in staging).
// 128x128 tile, BK=32, 4 waves (2x2). Out bf16 or f32.
// ---------------------------------------------------------------------------
template <bool A_BF16, bool OUT_BF16>
__global__ __launch_bounds__(256) void gemm_proj(
    const void* __restrict__ Ain, const float* __restrict__ Bf,
    const float* __restrict__ bias, void* __restrict__ Cout,
    int M, int N, int K) {
  __shared__ unsigned short As[128][40];
  __shared__ unsigned short Bs[128][40];
  const int t = threadIdx.x;
  const int lane = t & 63, wid = t >> 6;
  const int wm = wid >> 1, wn = wid & 1;
  const int l15 = lane & 15, l4 = lane >> 4;
  const int row0 = blockIdx.y * 128, col0 = blockIdx.x * 128;

  f32x4 acc[4][4];
#pragma unroll
  for (int i = 0; i < 4; i++)
#pragma unroll
    for (int j = 0; j < 4; j++) acc[i][j] = (f32x4){0.f, 0.f, 0.f, 0.f};

  for (int k0 = 0; k0 < K; k0 += 32) {
#pragma unroll
    for (int p = 0; p < 2; p++) {
      const int idx = t + p * 256;
      const int r = idx >> 2, kc = idx & 3;
      if (A_BF16) {
        *(uint4*)&As[r][kc * 8] = *(const uint4*)&(
            (const unsigned short*)Ain)[(size_t)(row0 + r) * K + k0 + kc * 8];
      } else {
        const float* Af = (const float*)Ain;
        const float4 v0 = *(const float4*)&Af[(size_t)(row0 + r) * K + k0 + kc * 8];
        const float4 v1 = *(const float4*)&Af[(size_t)(row0 + r) * K + k0 + kc * 8 + 4];
        uint4 w;
        w.x = pack2(v0.x, v0.y);
        w.y = pack2(v0.z, v0.w);
        w.z = pack2(v1.x, v1.y);
        w.w = pack2(v1.z, v1.w);
        *(uint4*)&As[r][kc * 8] = w;
      }
      {
        const float4 u0 = *(const float4*)&Bf[(size_t)(col0 + r) * K + k0 + kc * 8];
        const float4 u1 = *(const float4*)&Bf[(size_t)(col0 + r) * K + k0 + kc * 8 + 4];
        uint4 w;
        w.x = pack2(u0.x, u0.y);
        w.y = pack2(u0.z, u0.w);
        w.z = pack2(u1.x, u1.y);
        w.w = pack2(u1.z, u1.w);
        *(uint4*)&Bs[r][kc * 8] = w;
      }
    }
    __syncthreads();
    bf16x8 av[4], bv[4];
#pragma unroll
    for (int f = 0; f < 4; f++) {
      av[f] = *(const bf16x8*)&As[wm * 64 + f * 16 + l15][l4 * 8];
      bv[f] = *(const bf16x8*)&Bs[wn * 64 + f * 16 + l15][l4 * 8];
    }
#pragma unroll
    for (int fm = 0; fm < 4; fm++)
#pragma unroll
      for (int fn = 0; fn < 4; fn++)
        acc[fm][fn] = __builtin_amdgcn_mfma_f32_16x16x32_bf16(
            av[fm], bv[fn], acc[fm][fn], 0, 0, 0);
    __syncthreads();
  }

#pragma unroll
  for (int fm = 0; fm < 4; fm++) {
#pragma unroll
    for (int i = 0; i < 4; i++) {
      const int rr = row0 + wm * 64 + fm * 16 + l4 * 4 + i;
#pragma unroll
      for (int fn = 0; fn < 4; fn++) {
        const int c = col0 + wn * 64 + fn * 16 + l15;
        const float val = acc[fm][fn][i] + bias[c];
        if (OUT_BF16)
          ((unsigned short*)Cout)[(size_t)rr * N + c] = f2bf(val);
        else
          ((float*)Cout)[(size_t)rr * N + c] = val;
      }
    }
  }
}

// ---------------------------------------------------------------------------
// Transpose V head-slices: vT[z*64+d][k] = vb[b*TK+k][h*64+d], bf16.
// ---------------------------------------------------------------------------
__global__ __launch_bounds__(256) void transpose_v(
    const unsigned short* __restrict__ vb, unsigned short* __restrict__ vT) {
  const int z = blockIdx.z, b = z >> 4, h = z & 15;
  const int k0 = blockIdx.x * 64;
  __shared__ unsigned short Ts[64][68];
  const int t = threadIdx.x;
  const int c4 = (t & 15) * 4, r = t >> 4;
#pragma unroll
  for (int p = 0; p < 4; p++) {
    const int rr = r + p * 16;
    *(uint2*)&Ts[rr][c4] =
        *(const uint2*)&vb[(size_t)(b * TK + k0 + rr) * DIMSZ + h * HD + c4];
  }
  __syncthreads();
#pragma unroll
  for (int p = 0; p < 4; p++) {
    const int c2 = t + p * 256;
    const int d = c2 >> 4, k4 = (c2 & 15) * 4;
    uint2 o;
    o.x = (unsigned int)Ts[k4][d] | ((unsigned int)Ts[k4 + 1][d] << 16);
    o.y = (unsigned int)Ts[k4 + 2][d] | ((unsigned int)Ts[k4 + 3][d] << 16);
    *(uint2*)&vT[(size_t)(z * HD + d) * TK + k0 + k4] = o;
  }
}

// ---------------------------------------------------------------------------
// Fused attention middle: per block = 64 q-rows of one (b,h).
// Loop 1: recompute S via MFMA, accumulate per-row sum(exp(SCALE*s)).
// Loop 2: recompute S, p = exp*inv -> Pf (f32 LDS), coalesced nontemporal
//         write of attn, PV MFMA with fragments rebuilt from Pf.
// Grid: 1D 512 blocks, XCD-chunked swizzle (each XCD owns 4 whole z-slices,
// K+vT slice = 4 MB = its L2).
// ---------------------------------------------------------------------------
__global__ __launch_bounds__(256) void attn_fused(
    const unsigned short* __restrict__ qb, const unsigned short* __restrict__ kb,
    const unsigned short* __restrict__ vT, float* __restrict__ attn,
    unsigned short* __restrict__ aout) {
  // bijective XCD-chunk swizzle: nwg=512, chunk=64
  const int dsp = blockIdx.x;
  const int orig = (dsp & 7) * 64 + (dsp >> 3);
  const int z = orig >> 4, mb = orig & 15;
  const int b = z >> 4, h = z & 15;
  const int m0 = mb * 64;

  __shared__ unsigned short Qs[64][72];
  __shared__ unsigned short Ks[128][72];
  __shared__ unsigned short Vs[64][140];
  __shared__ float Pf[64][132];
  __shared__ float partial[64][2];
  __shared__ float rinv[64];

  const int t = threadIdx.x;
  const int lane = t & 63, wid = t >> 6;
  const int wm = wid >> 1, wn = wid & 1;
  const int l15 = lane & 15, l4 = lane >> 4;

  // stage Q [64][64]
#pragma unroll
  for (int p = 0; p < 2; p++) {
    const int idx = t + p * 256;
    const int r = idx >> 3, kc = idx & 7;
    *(uint4*)&Qs[r][kc * 8] =
        *(const uint4*)&qb[(size_t)(b * TQ + m0 + r) * DIMSZ + h * HD + kc * 8];
  }
  __syncthreads();
  bf16x8 aq[2][2];
#pragma unroll
  for (int fm = 0; fm < 2; fm++)
#pragma unroll
    for (int ks = 0; ks < 2; ks++)
      aq[fm][ks] = *(const bf16x8*)&Qs[wm * 32 + fm * 16 + l15][ks * 32 + l4 * 8];

  // ------------------ Loop 1: row sums ------------------
  float rsum[8];
#pragma unroll
  for (int r = 0; r < 8; r++) rsum[r] = 0.f;

  for (int kt = 0; kt < TK / 128; kt++) {
    __syncthreads();
#pragma unroll
    for (int p = 0; p < 4; p++) {
      const int idx = t + p * 256;
      const int r = idx >> 3, kc = idx & 7;
      *(uint4*)&Ks[r][kc * 8] = *(const uint4*)&kb[
          (size_t)(b * TK + kt * 128 + r) * DIMSZ + h * HD + kc * 8];
    }
    __syncthreads();
    bf16x8 bk_[4][2];
#pragma unroll
    for (int fn = 0; fn < 4; fn++)
#pragma unroll
      for (int ks = 0; ks < 2; ks++)
        bk_[fn][ks] =
            *(const bf16x8*)&Ks[wn * 64 + fn * 16 + l15][ks * 32 + l4 * 8];
    f32x4 acc_s[2][4];
#pragma unroll
    for (int i = 0; i < 2; i++)
#pragma unroll
      for (int j = 0; j < 4; j++) acc_s[i][j] = (f32x4){0.f, 0.f, 0.f, 0.f};
#pragma unroll
    for (int ks = 0; ks < 2; ks++)
#pragma unroll
      for (int fm = 0; fm < 2; fm++)
#pragma unroll
        for (int fn = 0; fn < 4; fn++)
          acc_s[fm][fn] = __builtin_amdgcn_mfma_f32_16x16x32_bf16(
              aq[fm][ks], bk_[fn][ks], acc_s[fm][fn], 0, 0, 0);
#pragma unroll
    for (int fm = 0; fm < 2; fm++)
#pragma unroll
      for (int i = 0; i < 4; i++) {
        float s = 0.f;
#pragma unroll
        for (int fn = 0; fn < 4; fn++) s += __expf(acc_s[fm][fn][i] * SCALE);
        rsum[fm * 4 + i] += s;
      }
  }
  // reduce over the 16 lanes of each row-group (l15)
#pragma unroll
  for (int off = 1; off < 16; off <<= 1)
#pragma unroll
    for (int r = 0; r < 8; r++) rsum[r] += __shfl_xor(rsum[r], off);
  if (l15 == 0) {
#pragma unroll
    for (int fm = 0; fm < 2; fm++)
#pragma unroll
      for (int i = 0; i < 4; i++)
        partial[wm * 32 + fm * 16 + l4 * 4 + i][wn] = rsum[fm * 4 + i];
  }
  __syncthreads();
  if (t < 64) rinv[t] = 1.f / (partial[t][0] + partial[t][1]);

  // ------------------ Loop 2: attn write + PV ------------------
  f32x4 acc_o[4];
#pragma unroll
  for (int j = 0; j < 4; j++) acc_o[j] = (f32x4){0.f, 0.f, 0.f, 0.f};

  float* attn_z = attn + (size_t)z * TQ * TK;

  for (int kt = 0; kt < TK / 128; kt++) {
    __syncthreads();
    // stage K tile [128 k-rows][64 d]
#pragma unroll
    for (int p = 0; p < 4; p++) {
      const int idx = t + p * 256;
      const int r = idx >> 3, kc = idx & 7;
      *(uint4*)&Ks[r][kc * 8] = *(const uint4*)&kb[
          (size_t)(b * TK + kt * 128 + r) * DIMSZ + h * HD + kc * 8];
    }
    // stage V tile [64 d][128 k]
#pragma unroll
    for (int p = 0; p < 4; p++) {
      const int idx = t + p * 256;
      const int d = idx >> 4, kc = idx & 15;
      *(uint4*)&Vs[d][kc * 8] =
          *(const uint4*)&vT[(size_t)(z * HD + d) * TK + kt * 128 + kc * 8];
    }
    __syncthreads();

    // S tile [64][128]
    bf16x8 bk_[4][2];
#pragma unroll
    for (int fn = 0; fn < 4; fn++)
#pragma unroll
      for (int ks = 0; ks < 2; ks++)
        bk_[fn][ks] =
            *(const bf16x8*)&Ks[wn * 64 + fn * 16 + l15][ks * 32 + l4 * 8];
    f32x4 acc_s[2][4];
#pragma unroll
    for (int i = 0; i < 2; i++)
#pragma unroll
      for (int j = 0; j < 4; j++) acc_s[i][j] = (f32x4){0.f, 0.f, 0.f, 0.f};
#pragma unroll
    for (int ks = 0; ks < 2; ks++)
#pragma unroll
      for (int fm = 0; fm < 2; fm++)
#pragma unroll
        for (int fn = 0; fn < 4; fn++)
          acc_s[fm][fn] = __builtin_amdgcn_mfma_f32_16x16x32_bf16(
              aq[fm][ks], bk_[fn][ks], acc_s[fm][fn], 0, 0, 0);

    // normalize -> Pf (exact f32)
#pragma unroll
    for (int fm = 0; fm < 2; fm++)
#pragma unroll
      for (int i = 0; i < 4; i++) {
        const int row = wm * 32 + fm * 16 + l4 * 4 + i;
        const float iv = rinv[row];
#pragma unroll
        for (int fn = 0; fn < 4; fn++) {
          const int col = wn * 64 + fn * 16 + l15;
          Pf[row][col] = __expf(acc_s[fm][fn][i] * SCALE) * iv;
        }
      }
    __syncthreads();

    // coalesced nontemporal attn write: 64 rows x 128 f32
#pragma unroll
    for (int it = 0; it < 8; it++) {
      const int idx = t + it * 256;
      const int row = idx >> 5, c4 = idx & 31;
      const f32x4 v = *(const f32x4*)&Pf[row][c4 * 4];
      __builtin_nontemporal_store(
          v, (f32x4*)&attn_z[(size_t)(m0 + row) * TK + kt * 128 + c4 * 4]);
    }

    // O += P[64x128] @ V[128x64], A-fragments rebuilt from Pf
#pragma unroll
    for (int ks2 = 0; ks2 < 4; ks2++) {
      const float* pr = &Pf[wid * 16 + l15][ks2 * 32 + l4 * 8];
      const float4 a0 = *(const float4*)pr;
      const float4 a1 = *(const float4*)(pr + 4);
      uint4 pk;
      pk.x = pack2(a0.x, a0.y);
      pk.y = pack2(a0.z, a0.w);
      pk.z = pack2(a1.x, a1.y);
      pk.w = pack2(a1.z, a1.w);
      const bf16x8 ap = *(const bf16x8*)&pk;
#pragma unroll
      for (int fn = 0; fn < 4; fn++) {
        const bf16x8 bvv =
            *(const bf16x8*)&Vs[fn * 16 + l15][ks2 * 32 + l4 * 8];
        acc_o[fn] = __builtin_amdgcn_mfma_f32_16x16x32_bf16(ap, bvv,
                                                            acc_o[fn], 0, 0, 0);
      }
    }
  }

#pragma unroll
  for (int fn = 0; fn < 4; fn++)
#pragma unroll
    for (int i = 0; i < 4; i++) {
      const int rr = m0 + wid * 16 + l4 * 4 + i;
      aout[(size_t)(b * TQ + rr) * DIMSZ + h * HD + fn * 16 + l15] =
          f2bf(acc_o[fn][i]);
    }
}

// ---------------------------------------------------------------------------
// Residual + LayerNorm (f32)
// ---------------------------------------------------------------------------
__global__ __launch_bounds__(256) void residual_ln(
    const float* __restrict__ q, const float* __restrict__ y,
    const float* __restrict__ gamma, const float* __restrict__ beta,
    float* __restrict__ out) {
  __shared__ float w1[4];
  __shared__ float w2[4];
  const size_t base = (size_t)blockIdx.x * DIMSZ;
  const int t = threadIdx.x;

  float x[4];
  float s = 0.f;
#pragma unroll
  for (int i = 0; i < 4; i++) {
    const int c = t + i * 256;
    x[i] = q[base + c] + y[base + c];
    s += x[i];
  }
#pragma unroll
  for (int off = 32; off; off >>= 1) s += __shfl_xor(s, off);
  if ((t & 63) == 0) w1[t >> 6] = s;
  __syncthreads();
  const float mean = (w1[0] + w1[1] + w1[2] + w1[3]) * (1.f / DIMSZ);

  float vs = 0.f;
#pragma unroll
  for (int i = 0; i < 4; i++) {
    const float d = x[i] - mean;
    vs += d * d;
  }
#pragma unroll
  for (int off = 32; off; off >>= 1) vs += __shfl_xor(vs, off);
  if ((t & 63) == 0) w2[t >> 6] = vs;
  __syncthreads();
  const float var = (w2[0] + w2[1] + w2[2] + w2[3]) * (1.f / DIMSZ);
  const float rstd = rsqrtf(var + 1e-5f);

#pragma unroll
  for (int i = 0; i < 4; i++) {
    const int c = t + i * 256;
    out[base + c] = (x[i] - mean) * rstd * gamma[c] + beta[c];
  }
}

// ---------------------------------------------------------------------------
extern "C" void kernel_launch(void* const* d_in, const int* in_sizes, int n_in,
                              void* d_out, int out_size, void* d_ws,
                              size_t ws_size, hipStream_t stream) {
  const float* query = (const float*)d_in[0];
  const float* key   = (const float*)d_in[1];
  const float* value = (const float*)d_in[2];
  const float* Wq = (const float*)d_in[3];
  const float* bq = (const float*)d_in[4];
  const float* Wk = (const float*)d_in[5];
  const float* bk = (const float*)d_in[6];
  const float* Wv = (const float*)d_in[7];
  const float* bv = (const float*)d_in[8];
  const float* Wo = (const float*)d_in[9];
  const float* bo = (const float*)d_in[10];
  const float* ln_gamma = (const float*)d_in[11];
  const float* ln_beta  = (const float*)d_in[12];

  float* out  = (float*)d_out;                    // [B, Tq, DIM] f32
  float* attn = out + (size_t)BATCH * TQ * DIMSZ; // [32, 1024, 4096] f32

  const size_t MQ = (size_t)BATCH * TQ * DIMSZ;   // 2M
  const size_t MK = (size_t)BATCH * TK * DIMSZ;   // 8M

  unsigned short* ws = (unsigned short*)d_ws;
  unsigned short* qb = ws;               // 4 MB
  unsigned short* kb = qb + MQ;          // 16 MB
  unsigned short* vb = kb + MK;          // 16 MB
  unsigned short* vT = vb + MK;          // 16 MB
  unsigned short* ab = vT + MK;          // 4 MB
  float* ybuf = (float*)(ab + MQ);       // 8 MB

  const dim3 blk(256);

  // Projections (fused f32->bf16 cast in staging)
  gemm_proj<false, true><<<dim3(DIMSZ / 128, (BATCH * TQ) / 128), blk, 0,
                           stream>>>(query, Wq, bq, qb, BATCH * TQ, DIMSZ,
                                     DIMSZ);
  gemm_proj<false, true><<<dim3(DIMSZ / 128, (BATCH * TK) / 128), blk, 0,
                           stream>>>(key, Wk, bk, kb, BATCH * TK, DIMSZ,
                                     DIMSZ);
  gemm_proj<false, true><<<dim3(DIMSZ / 128, (BATCH * TK) / 128), blk, 0,
                           stream>>>(value, Wv, bv, vb, BATCH * TK, DIMSZ,
                                     DIMSZ);

  transpose_v<<<dim3(TK / 64, 1, BATCH * NH), blk, 0, stream>>>(vb, vT);

  // Fused attention middle (stats + normalize + attn write + PV)
  attn_fused<<<dim3(512), blk, 0, stream>>>(qb, kb, vT, attn, ab);

  // Output projection (bf16 A, f32 weights, f32 out)
  gemm_proj<true, false><<<dim3(DIMSZ / 128, (BATCH * TQ) / 128), blk, 0,
                           stream>>>(ab, Wo, bo, ybuf, BATCH * TQ, DIMSZ,
                                     DIMSZ);

  residual_ln<<<dim3(BATCH * TQ), blk, 0, stream>>>(query, ybuf, ln_gamma,
                                                    ln_beta, out);
}